// Round 11
// baseline (167.578 us; speedup 1.0000x reference)
//
#include <hip/hip_runtime.h>
#include <hip/hip_bf16.h>
#include <math.h>

#define B_ 8
#define T_ 2048
#define E_ 1024
#define H_ 128
#define M_ (B_*T_)              // 16384
#define SCALE_ 45.25483399593904f   // sqrt(2048) per reference
#define SEG_ 4                      // key-range split factor for attention

typedef __attribute__((ext_vector_type(8))) short bf16x8;
typedef __attribute__((ext_vector_type(4))) float f32x4;

#define mfma16(A, Bv, C) __builtin_amdgcn_mfma_f32_16x16x32_bf16((A), (Bv), (C), 0, 0, 0)

// ---- fragment-order flat indices (ushort elements) -------------------------
// lane = quad*16 + l15 throughout.
#define FRAGW(g, kc, lane)  ((((size_t)(g)*32 + (kc))*64 + (lane))*8)
#define FRAGK(b, kt16, kc, lane) (((((size_t)(b)*128 + (kt16))*4 + (kc))*64 + (lane))*8)
#define FRAGV(b, ht, kt32, lane) (((((size_t)(b)*8 + (ht))*64 + (kt32))*64 + (lane))*8)

__device__ __forceinline__ ushort bf16_rne(float f) {
  unsigned u = __float_as_uint(f);
  u += 0x7fffu + ((u >> 16) & 1u);
  return (ushort)(u >> 16);
}
__device__ __forceinline__ float bf16_tof(ushort h) {
  return __uint_as_float(((unsigned)h) << 16);
}

// LDS-only barrier: drain DS ops but leave reg-destined global loads in flight.
__device__ __forceinline__ void lds_barrier() {
  asm volatile("s_waitcnt lgkmcnt(0)" ::: "memory");
  __builtin_amdgcn_s_barrier();
}

// ---------------------------------------------------------------------------
// Kernel 0: split W -> whT/wlT bf16 in PROJ-B FRAGMENT ORDER. (unchanged)
// ---------------------------------------------------------------------------
__global__ __launch_bounds__(256) void wsplit(
    const float* __restrict__ Wq, const float* __restrict__ Wk,
    const float* __restrict__ Wv,
    ushort* __restrict__ whT, ushort* __restrict__ wlT)
{
  const int idx  = blockIdx.x * 256 + threadIdx.x;  // 0..49151
  const int mat  = idx >> 14;
  const int rem  = idx & 16383;
  const int nt   = rem >> 11;
  const int kc   = (rem >> 6) & 31;
  const int lane = rem & 63;
  const int quad = lane >> 4, l15 = lane & 15;
  const float* W = (mat == 0) ? Wq : (mat == 1) ? Wk : Wv;
  const int n  = nt * 16 + l15;
  const int k0 = kc * 32 + quad * 8;
  bf16x8 hv, lv;
  #pragma unroll
  for (int j = 0; j < 8; ++j) {
    const float f = W[(size_t)(k0 + j) * H_ + n];
    const ushort h = bf16_rne(f);
    hv[j] = (short)h;
    lv[j] = (short)bf16_rne(f - bf16_tof(h));
  }
  *(bf16x8*)(whT + (size_t)idx * 8) = hv;
  *(bf16x8*)(wlT + (size_t)idx * 8) = lv;
}

// ---------------------------------------------------------------------------
// Kernel 1: fused QKV projection (round-17 BK=128 version, unchanged).
// ---------------------------------------------------------------------------
#define CVT8W(F0, F1, DSTOFF) do {                                            \
    const float f_[8] = {(F0).x, (F0).y, (F0).z, (F0).w,                      \
                         (F1).x, (F1).y, (F1).z, (F1).w};                     \
    bf16x8 hv_, lv_;                                                          \
    _Pragma("unroll")                                                         \
    for (int jj_ = 0; jj_ < 8; ++jj_) {                                       \
      const ushort h_ = bf16_rne(f_[jj_]);                                    \
      hv_[jj_] = (short)h_;                                                   \
      lv_[jj_] = (short)bf16_rne(f_[jj_] - bf16_tof(h_));                     \
    }                                                                         \
    *(bf16x8*)&SM[(DSTOFF) + ca * 8] = hv_;                                   \
    *(bf16x8*)&SM[(DSTOFF) + 2048 + ca * 8] = lv_;                            \
  } while (0)

#define APH(CUR, P, MT) (*(const bf16x8*)&SM[(CUR)*16384 + (P)*4096 + \
    (((MT)*4 + quad)*16 + (l15 ^ quad))*8])
#define ALH(CUR, P, MT) (*(const bf16x8*)&SM[(CUR)*16384 + (P)*4096 + 2048 + \
    (((MT)*4 + quad)*16 + (l15 ^ quad))*8])

// one kch phase: read A frags + 28 MFMA (3/3/1 product pattern)
#define MPHASE(CUR, P, BH0, BH1, BH2, BL0, BL1) do {                          \
    bf16x8 ah_[4], al_[4];                                                    \
    _Pragma("unroll")                                                         \
    for (int mt_ = 0; mt_ < 4; ++mt_) {                                       \
      ah_[mt_] = APH(CUR, P, mt_);                                            \
      al_[mt_] = ALH(CUR, P, mt_);                                            \
    }                                                                         \
    __builtin_amdgcn_s_setprio(1);                                            \
    _Pragma("unroll")                                                         \
    for (int mt_ = 0; mt_ < 4; ++mt_) {                                       \
      acc[0][mt_] = mfma16(ah_[mt_], BH0, acc[0][mt_]);                       \
      acc[0][mt_] = mfma16(ah_[mt_], BL0, acc[0][mt_]);                       \
      acc[0][mt_] = mfma16(al_[mt_], BH0, acc[0][mt_]);                       \
      acc[1][mt_] = mfma16(ah_[mt_], BH1, acc[1][mt_]);                       \
      acc[1][mt_] = mfma16(ah_[mt_], BL1, acc[1][mt_]);                       \
      acc[1][mt_] = mfma16(al_[mt_], BH1, acc[1][mt_]);                       \
      acc[2][mt_] = mfma16(ah_[mt_], BH2, acc[2][mt_]);                       \
    }                                                                         \
    __builtin_amdgcn_s_setprio(0);                                            \
  } while (0)

#define BLOADX(KCN0) do {                                                     \
    _Pragma("unroll")                                                         \
    for (int kch_ = 0; kch_ < 2; ++kch_) {                                    \
      const int kcn_ = (KCN0) + kch_;                                         \
      bhX[kch_*3+0] = *(const bf16x8*)(whT + FRAGW(gq,     kcn_, lane));      \
      bhX[kch_*3+1] = *(const bf16x8*)(whT + FRAGW(gq + 4, kcn_, lane));      \
      bhX[kch_*3+2] = *(const bf16x8*)(whT + FRAGW(gv,     kcn_, lane));      \
      blX[kch_*2+0] = *(const bf16x8*)(wlT + FRAGW(gq,     kcn_, lane));      \
      blX[kch_*2+1] = *(const bf16x8*)(wlT + FRAGW(gq + 4, kcn_, lane));      \
    }                                                                         \
  } while (0)

#define BLOADY(KCN0) do {                                                     \
    _Pragma("unroll")                                                         \
    for (int kch_ = 0; kch_ < 2; ++kch_) {                                    \
      const int kcn_ = (KCN0) + kch_;                                         \
      bhY[kch_*3+0] = *(const bf16x8*)(whT + FRAGW(gq,     kcn_, lane));      \
      bhY[kch_*3+1] = *(const bf16x8*)(whT + FRAGW(gq + 4, kcn_, lane));      \
      bhY[kch_*3+2] = *(const bf16x8*)(whT + FRAGW(gv,     kcn_, lane));      \
      blY[kch_*2+0] = *(const bf16x8*)(wlT + FRAGW(gq,     kcn_, lane));      \
      blY[kch_*2+1] = *(const bf16x8*)(wlT + FRAGW(gq + 4, kcn_, lane));      \
    }                                                                         \
  } while (0)

#define XLOAD(SOFF) do {                                                      \
    xf0 = *(const float4*)(xrow + (SOFF));                                    \
    xf1 = *(const float4*)(xrow + (SOFF) + 4);                                \
    xf2 = *(const float4*)(xrow + (SOFF) + 32);                               \
    xf3 = *(const float4*)(xrow + (SOFF) + 36);                               \
    xf4 = *(const float4*)(xrow + (SOFF) + 64);                               \
    xf5 = *(const float4*)(xrow + (SOFF) + 68);                               \
    xf6 = *(const float4*)(xrow + (SOFF) + 96);                               \
    xf7 = *(const float4*)(xrow + (SOFF) + 100);                              \
  } while (0)

#define PSTEP8(S, CUR, NXT) do {                                              \
    MPHASE(CUR, 0, bhX[0], bhX[1], bhX[2], blX[0], blX[1]);                   \
    MPHASE(CUR, 1, bhX[3], bhX[4], bhX[5], blX[2], blX[3]);                   \
    if ((S) + 1 < 8) {                                                        \
      BLOADX(4*((S)+1));                                                      \
      CVT8W(xf0, xf1, (NXT)*16384);                                           \
      CVT8W(xf2, xf3, (NXT)*16384 + 4096);                                    \
    }                                                                         \
    MPHASE(CUR, 2, bhY[0], bhY[1], bhY[2], blY[0], blY[1]);                   \
    MPHASE(CUR, 3, bhY[3], bhY[4], bhY[5], blY[2], blY[3]);                   \
    if ((S) + 1 < 8) {                                                        \
      BLOADY(4*((S)+1) + 2);                                                  \
      CVT8W(xf4, xf5, (NXT)*16384 + 8192);                                    \
      CVT8W(xf6, xf7, (NXT)*16384 + 12288);                                   \
    }                                                                         \
    if ((S) + 2 < 8) XLOAD(128*((S)+2));                                      \
    lds_barrier();                                                            \
  } while (0)

__global__ __launch_bounds__(256, 2) void proj_fused(
    const float* __restrict__ x,
    const ushort* __restrict__ whT, const ushort* __restrict__ wlT,
    ushort* __restrict__ qh, ushort* __restrict__ ql,
    ushort* __restrict__ kfh, ushort* __restrict__ kfl,
    ushort* __restrict__ vF)
{
  const int m0   = blockIdx.x * 64;
  const int half = blockIdx.y;
  const int tid  = threadIdx.x;
  const int wave = tid >> 6, lane = tid & 63;
  const int quad = lane >> 4, l15 = lane & 15;

  __shared__ __align__(16) ushort SM[32768]; // 64KB: 2 bufs x 4 kch x [Ah|Al]

  f32x4 acc[3][4];
  #pragma unroll
  for (int j = 0; j < 3; ++j)
    #pragma unroll
    for (int mt = 0; mt < 4; ++mt) acc[j][mt] = (f32x4){0.f, 0.f, 0.f, 0.f};

  const int arow  = tid >> 2;
  const int akoff = (tid & 3) * 8;
  const int ca    = ((arow >> 4) * 4 + (tid & 3)) * 16
                    + ((arow & 15) ^ (tid & 3));
  const int gq    = half * 8 + wave;
  const int gv    = 16 + half * 4 + wave;

  const float* xrow = x + (size_t)(m0 + arow) * E_ + akoff;

  float4 xf0, xf1, xf2, xf3, xf4, xf5, xf6, xf7;
  bf16x8 bhX[6], blX[4], bhY[6], blY[4];

  // ---- prologue: A(step0: kc0..3) -> buf0; xf(step1); B(step0) ----
  {
    const float4 a0 = *(const float4*)(xrow);
    const float4 a1 = *(const float4*)(xrow + 4);
    const float4 a2 = *(const float4*)(xrow + 32);
    const float4 a3 = *(const float4*)(xrow + 36);
    const float4 a4 = *(const float4*)(xrow + 64);
    const float4 a5 = *(const float4*)(xrow + 68);
    const float4 a6 = *(const float4*)(xrow + 96);
    const float4 a7 = *(const float4*)(xrow + 100);
    CVT8W(a0, a1, 0);
    CVT8W(a2, a3, 4096);
    CVT8W(a4, a5, 8192);
    CVT8W(a6, a7, 12288);
    XLOAD(128);
    BLOADX(0);
    BLOADY(2);
  }
  lds_barrier();

  int s = 0;
  while (true) {
    PSTEP8(s, 0, 1); if (++s == 8) break;
    PSTEP8(s, 1, 0); if (++s == 8) break;
  }

  // ---- epilogue: q (half0) / k (half1) via LDS transpose, 2 passes ----
  // TB = [64 rows][136 cols] ushort
  {
    ushort* TB = SM;
    const int colbase = wave * 16 + l15;       // + j*64 for second tile
    const int bb = m0 >> 11, t0 = m0 & 2047;
    #pragma unroll
    for (int pass = 0; pass < 2; ++pass) {
      __syncthreads();
      #pragma unroll
      for (int j = 0; j < 2; ++j)
        #pragma unroll
        for (int mt = 0; mt < 4; ++mt)
          #pragma unroll
          for (int r = 0; r < 4; ++r) {
            const float a = acc[j][mt][r];
            const ushort h = bf16_rne(a);
            const ushort val = pass ? bf16_rne(a - bf16_tof(h)) : h;
            TB[(mt * 16 + quad * 4 + r) * 136 + colbase + j * 64] = val;
          }
      __syncthreads();
      if (half == 0) {                         // q: row-major [t][h]
        const int row = tid >> 2, c0 = (tid & 3) * 32;
        ushort* dst = (pass ? ql : qh) + (size_t)(m0 + row) * H_ + c0;
        #pragma unroll
        for (int u = 0; u < 4; ++u)
          *(bf16x8*)(dst + u * 8) = *(const bf16x8*)&TB[row * 136 + c0 + u * 8];
      } else {                                 // k: contiguous FRAGK region
        ushort* dstb = (pass ? kfl : kfh) + FRAGK(bb, t0 >> 4, 0, 0) + tid * 32;
        const int kt16l = tid >> 6;
        const int kcc   = (tid >> 4) & 3;
        const int lane0 = (tid & 15) * 4;
        #pragma unroll
        for (int u = 0; u < 4; ++u) {
          const int l  = lane0 + u;
          const int key = kt16l * 16 + (l & 15);
          const int h0  = kcc * 32 + (l >> 4) * 8;
          *(bf16x8*)(dstb + u * 8) = *(const bf16x8*)&TB[key * 136 + h0];
        }
      }
    }
  }
  // ---- epilogue: v (both halves, 64 h-cols each) via LDS transpose ----
  __syncthreads();
  {
    ushort* smT = SM;                          // [64][72] local-h x t
    const int lh = wave * 16 + l15;
    #pragma unroll
    for (int mt = 0; mt < 4; ++mt)
      #pragma unroll
      for (int r = 0; r < 4; ++r)
        smT[lh * 72 + mt * 16 + quad * 4 + r] = bf16_rne(acc[2][mt][r]);
    __syncthreads();
    const int bb = m0 >> 11, t0 = m0 & 2047;
    #pragma unroll
    for (int u = 0; u < 2; ++u) {
      const int c    = u * 256 + tid;
      const int lht  = c >> 7;
      const int ktl  = (c >> 6) & 1;
      const int lv   = c & 63;
      const int qv   = lv >> 4, l15v = lv & 15;
      *(bf16x8*)(vF + FRAGV(bb, half * 4 + lht, (t0 >> 5) + ktl, lv)) =
          *(const bf16x8*)&smT[(lht * 16 + l15v) * 72 + ktl * 32 + qv * 8];
    }
  }
}

// ---------------------------------------------------------------------------
// Kernel 2: block flash attention, round-18: direct-L2 (r15) + wave-uniform
// rescale skip. When __all(pm <= mst), alpha == expf(0) == 1.0 exactly, so
// skipping the O-rescale / alpha exp / lst*alpha is BITWISE IDENTICAL while
// removing ~40 VALU ops from the serial softmax chain on most iterations.
// ---------------------------------------------------------------------------
__global__ __launch_bounds__(256) void attn_flash(
    const ushort* __restrict__ qh, const ushort* __restrict__ ql,
    const ushort* __restrict__ kfh, const ushort* __restrict__ kfl,
    const ushort* __restrict__ vF,
    ushort* __restrict__ Opart, float* __restrict__ mlpart)
{
  const int b    = (int)blockIdx.x & 7;        // %8 -> XCD pin
  const int seg  = (int)blockIdx.x >> 3;
  const int qt   = 31 - (int)blockIdx.y;       // heavy first
  const int q0   = qt * 64;
  const int tid  = threadIdx.x;
  const int wave = tid >> 6, lane = tid & 63;
  const int quad = lane >> 4, l15 = lane & 15;
  const f32x4 z4 = (f32x4){0.f, 0.f, 0.f, 0.f};

  __shared__ __align__(16) unsigned smPw[1280]; // 4 waves x [16 q][20 u32] P^T
  __shared__ __align__(16) ushort  smO[8704];   // 4 waves x [16 q][136]
  unsigned* pw = smPw + wave * 320;

  const int ntiles = 2 * qt + 2;
  const int cnt    = (ntiles + SEG_ - 1) >> 2;
  const int jt0    = seg * cnt;
  const int jt1    = (jt0 + cnt < ntiles) ? (jt0 + cnt) : ntiles;

  const int q0w = q0 + wave * 16;
  const int ntw = ((q0w + 15) >> 5) + 1;
  const size_t pidx = ((size_t)(b * 128 + qt * 4 + wave)) * SEG_ + seg;
  ushort* op = Opart + pidx * 2048;
  float*  ml = mlpart + pidx * 32;

  if (jt0 >= jt1) {                             // block-uniform early exit
    const bf16x8 zz = {0, 0, 0, 0, 0, 0, 0, 0};
    #pragma unroll
    for (int u = 0; u < 4; ++u)
      *(bf16x8*)(op + lane * 32 + u * 8) = zz;
    if (lane < 32) ml[lane] = (lane & 1) ? 0.f : -1e30f;
    return;
  }

  const size_t base = (size_t)b * T_ * H_;

  const ushort* qhp = qh + base + (size_t)(q0w + l15) * H_ + quad * 8;
  const ushort* qlp = ql + base + (size_t)(q0w + l15) * H_ + quad * 8;
  bf16x8 Qh[4], Ql[4];
  #pragma unroll
  for (int c = 0; c < 4; ++c) {
    Qh[c] = *(const bf16x8*)(qhp + c * 32);
    Ql[c] = *(const bf16x8*)(qlp + c * 32);
  }

  f32x4 O[8];                                   // O^T: h=ct*16+quad*4+r, q=l15
  #pragma unroll
  for (int i = 0; i < 8; ++i) O[i] = z4;
  float mst = -1e30f;                           // raw (unscaled) units
  float lst = 0.f;

  const size_t kvb = (size_t)b * 262144;
  const int jtc = (jt1 < ntw) ? jt1 : ntw;      // compute-tile end

  for (int jt = jt0; jt < jtc; ++jt) {
    const ushort* pKh = kfh + kvb + (size_t)jt * 4096;
    const ushort* pKl = kfl + kvb + (size_t)jt * 4096;
    const ushort* pV  = vF  + kvb + (size_t)jt * 512;
    const int k0 = jt * 32;

    f32x4 shh0 = z4, shh1 = z4, sx0 = z4, sx1 = z4;
    #pragma unroll
    for (int c = 0; c < 4; ++c) {
      const bf16x8 kh0 = *(const bf16x8*)(pKh + c * 512 + lane * 8);
      const bf16x8 kh1 = *(const bf16x8*)(pKh + (4 + c) * 512 + lane * 8);
      const bf16x8 kl0 = *(const bf16x8*)(pKl + c * 512 + lane * 8);
      const bf16x8 kl1 = *(const bf16x8*)(pKl + (4 + c) * 512 + lane * 8);
      shh0 = mfma16(kh0, Qh[c], shh0);          // A = K, B = Q  (swapped)
      shh1 = mfma16(kh1, Qh[c], shh1);
      sx0  = mfma16(kl0, Qh[c], sx0);
      sx1  = mfma16(kl1, Qh[c], sx1);
      sx0  = mfma16(kh0, Ql[c], sx0);
      sx1  = mfma16(kh1, Ql[c], sx1);
    }

    float r0[4], r1[4];                         // RAW scores
    #pragma unroll
    for (int r = 0; r < 4; ++r) {
      r0[r] = shh0[r] + sx0[r];
      r1[r] = shh1[r] + sx1[r];
    }
    if (jt == ntw - 1) {                        // causal: mask key > q
      const int base0 = q0w + l15 - k0 - quad * 4;
      #pragma unroll
      for (int r = 0; r < 4; ++r) {
        if (r > base0)      r0[r] = -1e30f;
        if (r > base0 - 16) r1[r] = -1e30f;
      }
    }

    float pm = fmaxf(fmaxf(fmaxf(r0[0], r0[1]), fmaxf(r0[2], r0[3])),
                     fmaxf(fmaxf(r1[0], r1[1]), fmaxf(r1[2], r1[3])));
    pm = fmaxf(pm, __shfl_xor(pm, 16));
    pm = fmaxf(pm, __shfl_xor(pm, 32));

    // wave-uniform rescale skip: if no lane's max grows, alpha == 1 exactly.
    const bool resc = !__all(pm <= mst);
    float mnew = mst, alpha = 1.f;
    if (resc) {
      mnew  = fmaxf(mst, pm);
      alpha = __expf((mst - mnew) * SCALE_);
      mst   = mnew;
    }

    float p0[4], p1[4];
    #pragma unroll
    for (int r = 0; r < 4; ++r) {
      p0[r] = __expf((r0[r] - mnew) * SCALE_);
      p1[r] = __expf((r1[r] - mnew) * SCALE_);
    }
    float sm = ((p0[0] + p0[1]) + (p0[2] + p0[3])) +
               ((p1[0] + p1[1]) + (p1[2] + p1[3]));
    sm += __shfl_xor(sm, 16);
    sm += __shfl_xor(sm, 32);

    const unsigned w0 = (unsigned)bf16_rne(p0[0]) | ((unsigned)bf16_rne(p0[1]) << 16);
    const unsigned w1 = (unsigned)bf16_rne(p0[2]) | ((unsigned)bf16_rne(p0[3]) << 16);
    const unsigned w2 = (unsigned)bf16_rne(p1[0]) | ((unsigned)bf16_rne(p1[1]) << 16);
    const unsigned w3 = (unsigned)bf16_rne(p1[2]) | ((unsigned)bf16_rne(p1[3]) << 16);
    *(unsigned long long*)&pw[l15 * 20 + 2 * quad] =
        (unsigned long long)w0 | ((unsigned long long)w1 << 32);
    *(unsigned long long*)&pw[l15 * 20 + 8 + 2 * quad] =
        (unsigned long long)w2 | ((unsigned long long)w3 << 32);

    if (resc) {
      lst = lst * alpha + sm;
      #pragma unroll
      for (int ct = 0; ct < 8; ++ct) {
        O[ct][0] *= alpha; O[ct][1] *= alpha;
        O[ct][2] *= alpha; O[ct][3] *= alpha;
      }
    } else {
      lst += sm;
    }

    const bf16x8 pB = *(const bf16x8*)&pw[l15 * 20 + 4 * quad];
    #pragma unroll
    for (int ct = 0; ct < 8; ++ct) {
      const bf16x8 vf = *(const bf16x8*)(pV + ct * 32768 + lane * 8);
      O[ct] = mfma16(vf, pB, O[ct]);            // A = V^T, B = P^T (swapped)
    }
  }

  // ---- epilogue: O^T -> [q][h] via per-wave LDS transpose (no barrier) ----
  {
    ushort* so = smO + wave * 2176;             // [16 q][136]
    #pragma unroll
    for (int ct = 0; ct < 8; ++ct)
      #pragma unroll
      for (int r = 0; r < 4; ++r)
        so[l15 * 136 + ct * 16 + quad * 4 + r] = bf16_rne(O[ct][r]);
    #pragma unroll
    for (int u = 0; u < 4; ++u) {
      const int q_ = u * 4 + quad;
      *(bf16x8*)(op + q_ * 128 + l15 * 8) =
          *(const bf16x8*)&so[q_ * 136 + l15 * 8];
    }
  }
  if (quad == 0) {
    ml[l15 * 2]     = mst * SCALE_;             // scaled units for combine
    ml[l15 * 2 + 1] = lst;
  }
}

// ---------------------------------------------------------------------------
// Kernel 3: combine 4 split-K partials per q-row.
//  round-18: skip Opart loads when w[s]==0 (empty/underflowed segments
//  contribute exactly 0) — bitwise identical, saves ~25% of partial reads.
// ---------------------------------------------------------------------------
__global__ __launch_bounds__(256) void attn_combine(
    const ushort* __restrict__ Opart, const float* __restrict__ mlpart,
    float* __restrict__ out)
{
  const int idx = blockIdx.x * 256 + threadIdx.x;
  const int c4  = idx & 31;
  const int r   = idx >> 5;
  const int t   = r & 2047;
  const int qt  = t >> 4, r16 = t & 15;
  const size_t pb = ((size_t)((r >> 11) * 128 + qt)) * SEG_;

  float m[SEG_], l[SEG_];
  #pragma unroll
  for (int s = 0; s < SEG_; ++s) {
    m[s] = mlpart[(pb + s) * 32 + r16 * 2];
    l[s] = mlpart[(pb + s) * 32 + r16 * 2 + 1];
  }
  float M = m[0];
  #pragma unroll
  for (int s = 1; s < SEG_; ++s) M = fmaxf(M, m[s]);
  float w[SEG_], L = 0.f;
  #pragma unroll
  for (int s = 0; s < SEG_; ++s) {
    w[s] = __expf(m[s] - M);
    L += l[s] * w[s];
  }
  float4 acc = make_float4(0.f, 0.f, 0.f, 0.f);
  #pragma unroll
  for (int s = 0; s < SEG_; ++s) {
    if (w[s] != 0.f) {                          // zero-weight: exact no-op
      const ushort4 o = *(const ushort4*)(Opart + (pb + s) * 2048 + r16 * 128 + c4 * 4);
      acc.x += w[s] * bf16_tof(o.x);
      acc.y += w[s] * bf16_tof(o.y);
      acc.z += w[s] * bf16_tof(o.z);
      acc.w += w[s] * bf16_tof(o.w);
    }
  }
  const float inv = 1.0f / L;
  *(float4*)(out + (size_t)r * H_ + c4 * 4) =
      make_float4(acc.x * inv, acc.y * inv, acc.z * inv, acc.w * inv);
}

// ---------------------------------------------------------------------------
extern "C" void kernel_launch(void* const* d_in, const int* in_sizes, int n_in,
                              void* d_out, int out_size, void* d_ws, size_t ws_size,
                              hipStream_t stream) {
  (void)in_sizes; (void)n_in; (void)out_size; (void)ws_size;
  const float* x  = (const float*)d_in[0];
  const float* Wq = (const float*)d_in[1];
  const float* Wk = (const float*)d_in[2];
  const float* Wv = (const float*)d_in[3];
  float* out = (float*)d_out;

  ushort* qhb = (ushort*)d_ws;
  ushort* qlb = qhb + (size_t)M_ * H_;
  ushort* kfh = qlb + (size_t)M_ * H_;
  ushort* kfl = kfh + (size_t)M_ * H_;
  ushort* vFb = kfl + (size_t)M_ * H_;
  ushort* whT = vFb + (size_t)M_ * H_;
  ushort* wlT = whT + (size_t)3 * H_ * E_;
  ushort* Opart = wlT + (size_t)3 * H_ * E_;
  float*  mlpart = (float*)(Opart + (size_t)B_ * 128 * SEG_ * 2048);

  wsplit<<<dim3(192), 256, 0, stream>>>(Wq, Wk, Wv, whT, wlT);
  proj_fused<<<dim3(M_/64, 2), 256, 0, stream>>>(x, whT, wlT,
                                                 qhb, qlb, kfh, kfl, vFb);
  attn_flash<<<dim3(B_*SEG_, 32), 256, 0, stream>>>(qhb, qlb, kfh, kfl, vFb,
                                                    Opart, mlpart);
  attn_combine<<<dim3(2048), 256, 0, stream>>>(Opart, mlpart, out);
}

// Round 12
// 162.760 us; speedup vs baseline: 1.0296x; 1.0296x over previous
//
#include <hip/hip_runtime.h>
#include <hip/hip_bf16.h>
#include <math.h>

#define B_ 8
#define T_ 2048
#define E_ 1024
#define H_ 128
#define M_ (B_*T_)              // 16384
#define SCALE_ 45.25483399593904f   // sqrt(2048) per reference
#define SEG_ 4                      // key-range split factor for attention

typedef __attribute__((ext_vector_type(8))) short bf16x8;
typedef __attribute__((ext_vector_type(4))) float f32x4;

#define mfma16(A, Bv, C) __builtin_amdgcn_mfma_f32_16x16x32_bf16((A), (Bv), (C), 0, 0, 0)

// ---- fragment-order flat indices (ushort elements) -------------------------
// lane = quad*16 + l15 throughout.
#define FRAGW(g, kc, lane)  ((((size_t)(g)*32 + (kc))*64 + (lane))*8)
#define FRAGK(b, kt16, kc, lane) (((((size_t)(b)*128 + (kt16))*4 + (kc))*64 + (lane))*8)
#define FRAGV(b, ht, kt32, lane) (((((size_t)(b)*8 + (ht))*64 + (kt32))*64 + (lane))*8)

__device__ __forceinline__ ushort bf16_rne(float f) {
  unsigned u = __float_as_uint(f);
  u += 0x7fffu + ((u >> 16) & 1u);
  return (ushort)(u >> 16);
}
__device__ __forceinline__ float bf16_tof(ushort h) {
  return __uint_as_float(((unsigned)h) << 16);
}

// LDS-only barrier: drain DS ops but leave reg-destined global loads in flight.
__device__ __forceinline__ void lds_barrier() {
  asm volatile("s_waitcnt lgkmcnt(0)" ::: "memory");
  __builtin_amdgcn_s_barrier();
}

// ---------------------------------------------------------------------------
// Kernel 0: split W -> whT/wlT bf16 in PROJ-B FRAGMENT ORDER. (unchanged)
// ---------------------------------------------------------------------------
__global__ __launch_bounds__(256) void wsplit(
    const float* __restrict__ Wq, const float* __restrict__ Wk,
    const float* __restrict__ Wv,
    ushort* __restrict__ whT, ushort* __restrict__ wlT)
{
  const int idx  = blockIdx.x * 256 + threadIdx.x;  // 0..49151
  const int mat  = idx >> 14;
  const int rem  = idx & 16383;
  const int nt   = rem >> 11;
  const int kc   = (rem >> 6) & 31;
  const int lane = rem & 63;
  const int quad = lane >> 4, l15 = lane & 15;
  const float* W = (mat == 0) ? Wq : (mat == 1) ? Wk : Wv;
  const int n  = nt * 16 + l15;
  const int k0 = kc * 32 + quad * 8;
  bf16x8 hv, lv;
  #pragma unroll
  for (int j = 0; j < 8; ++j) {
    const float f = W[(size_t)(k0 + j) * H_ + n];
    const ushort h = bf16_rne(f);
    hv[j] = (short)h;
    lv[j] = (short)bf16_rne(f - bf16_tof(h));
  }
  *(bf16x8*)(whT + (size_t)idx * 8) = hv;
  *(bf16x8*)(wlT + (size_t)idx * 8) = lv;
}

// ---------------------------------------------------------------------------
// Kernel 1: fused QKV projection (round-17 BK=128 version, unchanged).
// ---------------------------------------------------------------------------
#define CVT8W(F0, F1, DSTOFF) do {                                            \
    const float f_[8] = {(F0).x, (F0).y, (F0).z, (F0).w,                      \
                         (F1).x, (F1).y, (F1).z, (F1).w};                     \
    bf16x8 hv_, lv_;                                                          \
    _Pragma("unroll")                                                         \
    for (int jj_ = 0; jj_ < 8; ++jj_) {                                       \
      const ushort h_ = bf16_rne(f_[jj_]);                                    \
      hv_[jj_] = (short)h_;                                                   \
      lv_[jj_] = (short)bf16_rne(f_[jj_] - bf16_tof(h_));                     \
    }                                                                         \
    *(bf16x8*)&SM[(DSTOFF) + ca * 8] = hv_;                                   \
    *(bf16x8*)&SM[(DSTOFF) + 2048 + ca * 8] = lv_;                            \
  } while (0)

#define APH(CUR, P, MT) (*(const bf16x8*)&SM[(CUR)*16384 + (P)*4096 + \
    (((MT)*4 + quad)*16 + (l15 ^ quad))*8])
#define ALH(CUR, P, MT) (*(const bf16x8*)&SM[(CUR)*16384 + (P)*4096 + 2048 + \
    (((MT)*4 + quad)*16 + (l15 ^ quad))*8])

// one kch phase: read A frags + 28 MFMA (3/3/1 product pattern)
#define MPHASE(CUR, P, BH0, BH1, BH2, BL0, BL1) do {                          \
    bf16x8 ah_[4], al_[4];                                                    \
    _Pragma("unroll")                                                         \
    for (int mt_ = 0; mt_ < 4; ++mt_) {                                       \
      ah_[mt_] = APH(CUR, P, mt_);                                            \
      al_[mt_] = ALH(CUR, P, mt_);                                            \
    }                                                                         \
    __builtin_amdgcn_s_setprio(1);                                            \
    _Pragma("unroll")                                                         \
    for (int mt_ = 0; mt_ < 4; ++mt_) {                                       \
      acc[0][mt_] = mfma16(ah_[mt_], BH0, acc[0][mt_]);                       \
      acc[0][mt_] = mfma16(ah_[mt_], BL0, acc[0][mt_]);                       \
      acc[0][mt_] = mfma16(al_[mt_], BH0, acc[0][mt_]);                       \
      acc[1][mt_] = mfma16(ah_[mt_], BH1, acc[1][mt_]);                       \
      acc[1][mt_] = mfma16(ah_[mt_], BL1, acc[1][mt_]);                       \
      acc[1][mt_] = mfma16(al_[mt_], BH1, acc[1][mt_]);                       \
      acc[2][mt_] = mfma16(ah_[mt_], BH2, acc[2][mt_]);                       \
    }                                                                         \
    __builtin_amdgcn_s_setprio(0);                                            \
  } while (0)

#define BLOADX(KCN0) do {                                                     \
    _Pragma("unroll")                                                         \
    for (int kch_ = 0; kch_ < 2; ++kch_) {                                    \
      const int kcn_ = (KCN0) + kch_;                                         \
      bhX[kch_*3+0] = *(const bf16x8*)(whT + FRAGW(gq,     kcn_, lane));      \
      bhX[kch_*3+1] = *(const bf16x8*)(whT + FRAGW(gq + 4, kcn_, lane));      \
      bhX[kch_*3+2] = *(const bf16x8*)(whT + FRAGW(gv,     kcn_, lane));      \
      blX[kch_*2+0] = *(const bf16x8*)(wlT + FRAGW(gq,     kcn_, lane));      \
      blX[kch_*2+1] = *(const bf16x8*)(wlT + FRAGW(gq + 4, kcn_, lane));      \
    }                                                                         \
  } while (0)

#define BLOADY(KCN0) do {                                                     \
    _Pragma("unroll")                                                         \
    for (int kch_ = 0; kch_ < 2; ++kch_) {                                    \
      const int kcn_ = (KCN0) + kch_;                                         \
      bhY[kch_*3+0] = *(const bf16x8*)(whT + FRAGW(gq,     kcn_, lane));      \
      bhY[kch_*3+1] = *(const bf16x8*)(whT + FRAGW(gq + 4, kcn_, lane));      \
      bhY[kch_*3+2] = *(const bf16x8*)(whT + FRAGW(gv,     kcn_, lane));      \
      blY[kch_*2+0] = *(const bf16x8*)(wlT + FRAGW(gq,     kcn_, lane));      \
      blY[kch_*2+1] = *(const bf16x8*)(wlT + FRAGW(gq + 4, kcn_, lane));      \
    }                                                                         \
  } while (0)

#define XLOAD(SOFF) do {                                                      \
    xf0 = *(const float4*)(xrow + (SOFF));                                    \
    xf1 = *(const float4*)(xrow + (SOFF) + 4);                                \
    xf2 = *(const float4*)(xrow + (SOFF) + 32);                               \
    xf3 = *(const float4*)(xrow + (SOFF) + 36);                               \
    xf4 = *(const float4*)(xrow + (SOFF) + 64);                               \
    xf5 = *(const float4*)(xrow + (SOFF) + 68);                               \
    xf6 = *(const float4*)(xrow + (SOFF) + 96);                               \
    xf7 = *(const float4*)(xrow + (SOFF) + 100);                              \
  } while (0)

#define PSTEP8(S, CUR, NXT) do {                                              \
    MPHASE(CUR, 0, bhX[0], bhX[1], bhX[2], blX[0], blX[1]);                   \
    MPHASE(CUR, 1, bhX[3], bhX[4], bhX[5], blX[2], blX[3]);                   \
    if ((S) + 1 < 8) {                                                        \
      BLOADX(4*((S)+1));                                                      \
      CVT8W(xf0, xf1, (NXT)*16384);                                           \
      CVT8W(xf2, xf3, (NXT)*16384 + 4096);                                    \
    }                                                                         \
    MPHASE(CUR, 2, bhY[0], bhY[1], bhY[2], blY[0], blY[1]);                   \
    MPHASE(CUR, 3, bhY[3], bhY[4], bhY[5], blY[2], blY[3]);                   \
    if ((S) + 1 < 8) {                                                        \
      BLOADY(4*((S)+1) + 2);                                                  \
      CVT8W(xf4, xf5, (NXT)*16384 + 8192);                                    \
      CVT8W(xf6, xf7, (NXT)*16384 + 12288);                                   \
    }                                                                         \
    if ((S) + 2 < 8) XLOAD(128*((S)+2));                                      \
    lds_barrier();                                                            \
  } while (0)

__global__ __launch_bounds__(256, 2) void proj_fused(
    const float* __restrict__ x,
    const ushort* __restrict__ whT, const ushort* __restrict__ wlT,
    ushort* __restrict__ qh, ushort* __restrict__ ql,
    ushort* __restrict__ kfh, ushort* __restrict__ kfl,
    ushort* __restrict__ vF)
{
  const int m0   = blockIdx.x * 64;
  const int half = blockIdx.y;
  const int tid  = threadIdx.x;
  const int wave = tid >> 6, lane = tid & 63;
  const int quad = lane >> 4, l15 = lane & 15;

  __shared__ __align__(16) ushort SM[32768]; // 64KB: 2 bufs x 4 kch x [Ah|Al]

  f32x4 acc[3][4];
  #pragma unroll
  for (int j = 0; j < 3; ++j)
    #pragma unroll
    for (int mt = 0; mt < 4; ++mt) acc[j][mt] = (f32x4){0.f, 0.f, 0.f, 0.f};

  const int arow  = tid >> 2;
  const int akoff = (tid & 3) * 8;
  const int ca    = ((arow >> 4) * 4 + (tid & 3)) * 16
                    + ((arow & 15) ^ (tid & 3));
  const int gq    = half * 8 + wave;
  const int gv    = 16 + half * 4 + wave;

  const float* xrow = x + (size_t)(m0 + arow) * E_ + akoff;

  float4 xf0, xf1, xf2, xf3, xf4, xf5, xf6, xf7;
  bf16x8 bhX[6], blX[4], bhY[6], blY[4];

  // ---- prologue: A(step0: kc0..3) -> buf0; xf(step1); B(step0) ----
  {
    const float4 a0 = *(const float4*)(xrow);
    const float4 a1 = *(const float4*)(xrow + 4);
    const float4 a2 = *(const float4*)(xrow + 32);
    const float4 a3 = *(const float4*)(xrow + 36);
    const float4 a4 = *(const float4*)(xrow + 64);
    const float4 a5 = *(const float4*)(xrow + 68);
    const float4 a6 = *(const float4*)(xrow + 96);
    const float4 a7 = *(const float4*)(xrow + 100);
    CVT8W(a0, a1, 0);
    CVT8W(a2, a3, 4096);
    CVT8W(a4, a5, 8192);
    CVT8W(a6, a7, 12288);
    XLOAD(128);
    BLOADX(0);
    BLOADY(2);
  }
  lds_barrier();

  int s = 0;
  while (true) {
    PSTEP8(s, 0, 1); if (++s == 8) break;
    PSTEP8(s, 1, 0); if (++s == 8) break;
  }

  // ---- epilogue: q (half0) / k (half1) via LDS transpose, 2 passes ----
  // TB = [64 rows][136 cols] ushort
  {
    ushort* TB = SM;
    const int colbase = wave * 16 + l15;       // + j*64 for second tile
    const int bb = m0 >> 11, t0 = m0 & 2047;
    #pragma unroll
    for (int pass = 0; pass < 2; ++pass) {
      __syncthreads();
      #pragma unroll
      for (int j = 0; j < 2; ++j)
        #pragma unroll
        for (int mt = 0; mt < 4; ++mt)
          #pragma unroll
          for (int r = 0; r < 4; ++r) {
            const float a = acc[j][mt][r];
            const ushort h = bf16_rne(a);
            const ushort val = pass ? bf16_rne(a - bf16_tof(h)) : h;
            TB[(mt * 16 + quad * 4 + r) * 136 + colbase + j * 64] = val;
          }
      __syncthreads();
      if (half == 0) {                         // q: row-major [t][h]
        const int row = tid >> 2, c0 = (tid & 3) * 32;
        ushort* dst = (pass ? ql : qh) + (size_t)(m0 + row) * H_ + c0;
        #pragma unroll
        for (int u = 0; u < 4; ++u)
          *(bf16x8*)(dst + u * 8) = *(const bf16x8*)&TB[row * 136 + c0 + u * 8];
      } else {                                 // k: contiguous FRAGK region
        ushort* dstb = (pass ? kfl : kfh) + FRAGK(bb, t0 >> 4, 0, 0) + tid * 32;
        const int kt16l = tid >> 6;
        const int kcc   = (tid >> 4) & 3;
        const int lane0 = (tid & 15) * 4;
        #pragma unroll
        for (int u = 0; u < 4; ++u) {
          const int l  = lane0 + u;
          const int key = kt16l * 16 + (l & 15);
          const int h0  = kcc * 32 + (l >> 4) * 8;
          *(bf16x8*)(dstb + u * 8) = *(const bf16x8*)&TB[key * 136 + h0];
        }
      }
    }
  }
  // ---- epilogue: v (both halves, 64 h-cols each) via LDS transpose ----
  __syncthreads();
  {
    ushort* smT = SM;                          // [64][72] local-h x t
    const int lh = wave * 16 + l15;
    #pragma unroll
    for (int mt = 0; mt < 4; ++mt)
      #pragma unroll
      for (int r = 0; r < 4; ++r)
        smT[lh * 72 + mt * 16 + quad * 4 + r] = bf16_rne(acc[2][mt][r]);
    __syncthreads();
    const int bb = m0 >> 11, t0 = m0 & 2047;
    #pragma unroll
    for (int u = 0; u < 2; ++u) {
      const int c    = u * 256 + tid;
      const int lht  = c >> 7;
      const int ktl  = (c >> 6) & 1;
      const int lv   = c & 63;
      const int qv   = lv >> 4, l15v = lv & 15;
      *(bf16x8*)(vF + FRAGV(bb, half * 4 + lht, (t0 >> 5) + ktl, lv)) =
          *(const bf16x8*)&smT[(lht * 16 + l15v) * 72 + ktl * 32 + qv * 8];
    }
  }
}

// ---------------------------------------------------------------------------
// Kernel 2: block flash attention (round-15/17 direct-L2 version — the
// straight-line r10 softmax restored; r18's rescale-skip branch REVERTED:
// it fenced the compiler's load pipelining in the hot loop, net −2 µs).
// ---------------------------------------------------------------------------
__global__ __launch_bounds__(256) void attn_flash(
    const ushort* __restrict__ qh, const ushort* __restrict__ ql,
    const ushort* __restrict__ kfh, const ushort* __restrict__ kfl,
    const ushort* __restrict__ vF,
    ushort* __restrict__ Opart, float* __restrict__ mlpart)
{
  const int b    = (int)blockIdx.x & 7;        // %8 -> XCD pin
  const int seg  = (int)blockIdx.x >> 3;
  const int qt   = 31 - (int)blockIdx.y;       // heavy first
  const int q0   = qt * 64;
  const int tid  = threadIdx.x;
  const int wave = tid >> 6, lane = tid & 63;
  const int quad = lane >> 4, l15 = lane & 15;
  const f32x4 z4 = (f32x4){0.f, 0.f, 0.f, 0.f};

  __shared__ __align__(16) unsigned smPw[1280]; // 4 waves x [16 q][20 u32] P^T
  __shared__ __align__(16) ushort  smO[8704];   // 4 waves x [16 q][136]
  unsigned* pw = smPw + wave * 320;

  const int ntiles = 2 * qt + 2;
  const int cnt    = (ntiles + SEG_ - 1) >> 2;
  const int jt0    = seg * cnt;
  const int jt1    = (jt0 + cnt < ntiles) ? (jt0 + cnt) : ntiles;

  const int q0w = q0 + wave * 16;
  const int ntw = ((q0w + 15) >> 5) + 1;
  const size_t pidx = ((size_t)(b * 128 + qt * 4 + wave)) * SEG_ + seg;
  ushort* op = Opart + pidx * 2048;
  float*  ml = mlpart + pidx * 32;

  if (jt0 >= jt1) {                             // block-uniform early exit
    const bf16x8 zz = {0, 0, 0, 0, 0, 0, 0, 0};
    #pragma unroll
    for (int u = 0; u < 4; ++u)
      *(bf16x8*)(op + lane * 32 + u * 8) = zz;
    if (lane < 32) ml[lane] = (lane & 1) ? 0.f : -1e30f;
    return;
  }

  const size_t base = (size_t)b * T_ * H_;

  const ushort* qhp = qh + base + (size_t)(q0w + l15) * H_ + quad * 8;
  const ushort* qlp = ql + base + (size_t)(q0w + l15) * H_ + quad * 8;
  bf16x8 Qh[4], Ql[4];
  #pragma unroll
  for (int c = 0; c < 4; ++c) {
    Qh[c] = *(const bf16x8*)(qhp + c * 32);
    Ql[c] = *(const bf16x8*)(qlp + c * 32);
  }

  f32x4 O[8];                                   // O^T: h=ct*16+quad*4+r, q=l15
  #pragma unroll
  for (int i = 0; i < 8; ++i) O[i] = z4;
  float mst = -1e30f;                           // raw (unscaled) units
  float lst = 0.f;

  const size_t kvb = (size_t)b * 262144;
  const int jtc = (jt1 < ntw) ? jt1 : ntw;      // compute-tile end

  for (int jt = jt0; jt < jtc; ++jt) {
    const ushort* pKh = kfh + kvb + (size_t)jt * 4096;
    const ushort* pKl = kfl + kvb + (size_t)jt * 4096;
    const ushort* pV  = vF  + kvb + (size_t)jt * 512;
    const int k0 = jt * 32;

    f32x4 shh0 = z4, shh1 = z4, sx0 = z4, sx1 = z4;
    #pragma unroll
    for (int c = 0; c < 4; ++c) {
      const bf16x8 kh0 = *(const bf16x8*)(pKh + c * 512 + lane * 8);
      const bf16x8 kh1 = *(const bf16x8*)(pKh + (4 + c) * 512 + lane * 8);
      const bf16x8 kl0 = *(const bf16x8*)(pKl + c * 512 + lane * 8);
      const bf16x8 kl1 = *(const bf16x8*)(pKl + (4 + c) * 512 + lane * 8);
      shh0 = mfma16(kh0, Qh[c], shh0);          // A = K, B = Q  (swapped)
      shh1 = mfma16(kh1, Qh[c], shh1);
      sx0  = mfma16(kl0, Qh[c], sx0);
      sx1  = mfma16(kl1, Qh[c], sx1);
      sx0  = mfma16(kh0, Ql[c], sx0);
      sx1  = mfma16(kh1, Ql[c], sx1);
    }

    float r0[4], r1[4];                         // RAW scores
    #pragma unroll
    for (int r = 0; r < 4; ++r) {
      r0[r] = shh0[r] + sx0[r];
      r1[r] = shh1[r] + sx1[r];
    }
    if (jt == ntw - 1) {                        // causal: mask key > q
      const int base0 = q0w + l15 - k0 - quad * 4;
      #pragma unroll
      for (int r = 0; r < 4; ++r) {
        if (r > base0)      r0[r] = -1e30f;
        if (r > base0 - 16) r1[r] = -1e30f;
      }
    }

    float pm = fmaxf(fmaxf(fmaxf(r0[0], r0[1]), fmaxf(r0[2], r0[3])),
                     fmaxf(fmaxf(r1[0], r1[1]), fmaxf(r1[2], r1[3])));
    pm = fmaxf(pm, __shfl_xor(pm, 16));
    pm = fmaxf(pm, __shfl_xor(pm, 32));

    const float mnew  = fmaxf(mst, pm);
    const float alpha = __expf((mst - mnew) * SCALE_);
    mst = mnew;

    float p0[4], p1[4];
    #pragma unroll
    for (int r = 0; r < 4; ++r) {
      p0[r] = __expf((r0[r] - mnew) * SCALE_);
      p1[r] = __expf((r1[r] - mnew) * SCALE_);
    }
    float sm = ((p0[0] + p0[1]) + (p0[2] + p0[3])) +
               ((p1[0] + p1[1]) + (p1[2] + p1[3]));
    sm += __shfl_xor(sm, 16);
    sm += __shfl_xor(sm, 32);
    lst = lst * alpha + sm;

    const unsigned w0 = (unsigned)bf16_rne(p0[0]) | ((unsigned)bf16_rne(p0[1]) << 16);
    const unsigned w1 = (unsigned)bf16_rne(p0[2]) | ((unsigned)bf16_rne(p0[3]) << 16);
    const unsigned w2 = (unsigned)bf16_rne(p1[0]) | ((unsigned)bf16_rne(p1[1]) << 16);
    const unsigned w3 = (unsigned)bf16_rne(p1[2]) | ((unsigned)bf16_rne(p1[3]) << 16);
    *(unsigned long long*)&pw[l15 * 20 + 2 * quad] =
        (unsigned long long)w0 | ((unsigned long long)w1 << 32);
    *(unsigned long long*)&pw[l15 * 20 + 8 + 2 * quad] =
        (unsigned long long)w2 | ((unsigned long long)w3 << 32);

    #pragma unroll
    for (int ct = 0; ct < 8; ++ct) {
      O[ct][0] *= alpha; O[ct][1] *= alpha;
      O[ct][2] *= alpha; O[ct][3] *= alpha;
    }
    const bf16x8 pB = *(const bf16x8*)&pw[l15 * 20 + 4 * quad];
    #pragma unroll
    for (int ct = 0; ct < 8; ++ct) {
      const bf16x8 vf = *(const bf16x8*)(pV + ct * 32768 + lane * 8);
      O[ct] = mfma16(vf, pB, O[ct]);            // A = V^T, B = P^T (swapped)
    }
  }

  // ---- epilogue: O^T -> [q][h] via per-wave LDS transpose (no barrier) ----
  {
    ushort* so = smO + wave * 2176;             // [16 q][136]
    #pragma unroll
    for (int ct = 0; ct < 8; ++ct)
      #pragma unroll
      for (int r = 0; r < 4; ++r)
        so[l15 * 136 + ct * 16 + quad * 4 + r] = bf16_rne(O[ct][r]);
    #pragma unroll
    for (int u = 0; u < 4; ++u) {
      const int q_ = u * 4 + quad;
      *(bf16x8*)(op + q_ * 128 + l15 * 8) =
          *(const bf16x8*)&so[q_ * 136 + l15 * 8];
    }
  }
  if (quad == 0) {
    ml[l15 * 2]     = mst * SCALE_;             // scaled units for combine
    ml[l15 * 2 + 1] = lst;
  }
}

// ---------------------------------------------------------------------------
// Kernel 3: combine 4 split-K partials per q-row (keeps r18's zero-weight
// skip: empty/underflowed segments contribute exactly 0 — bitwise identical,
// ~25% fewer partial reads in a BW-bound kernel).
// ---------------------------------------------------------------------------
__global__ __launch_bounds__(256) void attn_combine(
    const ushort* __restrict__ Opart, const float* __restrict__ mlpart,
    float* __restrict__ out)
{
  const int idx = blockIdx.x * 256 + threadIdx.x;
  const int c4  = idx & 31;
  const int r   = idx >> 5;
  const int t   = r & 2047;
  const int qt  = t >> 4, r16 = t & 15;
  const size_t pb = ((size_t)((r >> 11) * 128 + qt)) * SEG_;

  float m[SEG_], l[SEG_];
  #pragma unroll
  for (int s = 0; s < SEG_; ++s) {
    m[s] = mlpart[(pb + s) * 32 + r16 * 2];
    l[s] = mlpart[(pb + s) * 32 + r16 * 2 + 1];
  }
  float M = m[0];
  #pragma unroll
  for (int s = 1; s < SEG_; ++s) M = fmaxf(M, m[s]);
  float w[SEG_], L = 0.f;
  #pragma unroll
  for (int s = 0; s < SEG_; ++s) {
    w[s] = __expf(m[s] - M);
    L += l[s] * w[s];
  }
  float4 acc = make_float4(0.f, 0.f, 0.f, 0.f);
  #pragma unroll
  for (int s = 0; s < SEG_; ++s) {
    if (w[s] != 0.f) {                          // zero-weight: exact no-op
      const ushort4 o = *(const ushort4*)(Opart + (pb + s) * 2048 + r16 * 128 + c4 * 4);
      acc.x += w[s] * bf16_tof(o.x);
      acc.y += w[s] * bf16_tof(o.y);
      acc.z += w[s] * bf16_tof(o.z);
      acc.w += w[s] * bf16_tof(o.w);
    }
  }
  const float inv = 1.0f / L;
  *(float4*)(out + (size_t)r * H_ + c4 * 4) =
      make_float4(acc.x * inv, acc.y * inv, acc.z * inv, acc.w * inv);
}

// ---------------------------------------------------------------------------
extern "C" void kernel_launch(void* const* d_in, const int* in_sizes, int n_in,
                              void* d_out, int out_size, void* d_ws, size_t ws_size,
                              hipStream_t stream) {
  (void)in_sizes; (void)n_in; (void)out_size; (void)ws_size;
  const float* x  = (const float*)d_in[0];
  const float* Wq = (const float*)d_in[1];
  const float* Wk = (const float*)d_in[2];
  const float* Wv = (const float*)d_in[3];
  float* out = (float*)d_out;

  ushort* qhb = (ushort*)d_ws;
  ushort* qlb = qhb + (size_t)M_ * H_;
  ushort* kfh = qlb + (size_t)M_ * H_;
  ushort* kfl = kfh + (size_t)M_ * H_;
  ushort* vFb = kfl + (size_t)M_ * H_;
  ushort* whT = vFb + (size_t)M_ * H_;
  ushort* wlT = whT + (size_t)3 * H_ * E_;
  ushort* Opart = wlT + (size_t)3 * H_ * E_;
  float*  mlpart = (float*)(Opart + (size_t)B_ * 128 * SEG_ * 2048);

  wsplit<<<dim3(192), 256, 0, stream>>>(Wq, Wk, Wv, whT, wlT);
  proj_fused<<<dim3(M_/64, 2), 256, 0, stream>>>(x, whT, wlT,
                                                 qhb, qlb, kfh, kfl, vFb);
  attn_flash<<<dim3(B_*SEG_, 32), 256, 0, stream>>>(qhb, qlb, kfh, kfl, vFb,
                                                    Opart, mlpart);
  attn_combine<<<dim3(2048), 256, 0, stream>>>(Opart, mlpart, out);
}